// Round 9
// baseline (4659.717 us; speedup 1.0000x reference)
//
#include <hip/hip_runtime.h>
#include <stdint.h>

#define MDIM 8192
#define NDIM 16384
#define KDIM 4096
#define NT   64          // K-steps of 64

typedef __attribute__((ext_vector_type(4))) int i32x4;

__device__ __forceinline__ void gload_lds16(const void* g, void* l) {
    __builtin_amdgcn_global_load_lds(
        (const __attribute__((address_space(1))) void*)g,
        (__attribute__((address_space(3))) void*)l,
        16, 0, 0);
}

__device__ __forceinline__ i32x4 MFMA8(i32x4 a, i32x4 b, i32x4 c) {
    return __builtin_amdgcn_mfma_i32_16x16x64_i8(a, b, c, 0, 0, 0);
}

// ---------------- quantization kernels (unchanged, round-6 verified) ----------------

__global__ __launch_bounds__(256)
void quant_x_kernel(const float* __restrict__ x, int8_t* __restrict__ xq,
                    float* __restrict__ sx) {
    const int row = (int)blockIdx.x;
    const float* xr = x + (long)row * KDIM;
    const int t = threadIdx.x;
    float v[16];
#pragma unroll
    for (int i = 0; i < 4; ++i)
        *(float4*)&v[i * 4] = ((const float4*)xr)[t + 256 * i];
    float m = 0.f;
#pragma unroll
    for (int i = 0; i < 16; ++i) m = fmaxf(m, fabsf(v[i]));
#pragma unroll
    for (int off = 32; off >= 1; off >>= 1) m = fmaxf(m, __shfl_xor(m, off));
    __shared__ float red[4];
    if ((t & 63) == 0) red[t >> 6] = m;
    __syncthreads();
    m = fmaxf(fmaxf(red[0], red[1]), fmaxf(red[2], red[3]));
    m = fmaxf(m, 1e-20f);
    const float inv = 127.0f / m;
    if (t == 0) sx[row] = m * (1.0f / 127.0f);
    int* qo = (int*)(xq + (long)row * KDIM);
#pragma unroll
    for (int i = 0; i < 4; ++i) {
        union { int8_t c[4]; int w; } o;
#pragma unroll
        for (int j = 0; j < 4; ++j)
            o.c[j] = (int8_t)__float2int_rn(v[i * 4 + j] * inv);
        qo[t + 256 * i] = o.w;
    }
}

__global__ __launch_bounds__(256)
void quant_w_kernel(const int* __restrict__ q, const int* __restrict__ zp,
                    int8_t* __restrict__ wq) {
    const long i = (long)blockIdx.x * 256 + threadIdx.x;
    const long e = i * 16;
    const int o = (int)(e >> 12);          // KDIM = 4096
    const int z = zp[o];
    union { int8_t c[16]; int4 v; } r;
#pragma unroll
    for (int b = 0; b < 4; ++b) {
        int4 a = ((const int4*)(q + e))[b];
        r.c[b * 4 + 0] = (int8_t)(a.x - z);
        r.c[b * 4 + 1] = (int8_t)(a.y - z);
        r.c[b * 4 + 2] = (int8_t)(a.z - z);
        r.c[b * 4 + 3] = (int8_t)(a.w - z);
    }
    *(int4*)(wq + e) = r.v;
}

// ------ 256x256 8-wave int8 MFMA GEMM, DOUBLE-buffered, 2 blocks/CU (m97-style) ------
// C[m,n] = scale[n] * sx[m] * sum_k xq[m,k] * wq[n,k]   (i32 accum, exact)
// LDS: 2 bufs x (A plane 16 KB + B plane 16 KB) = 64 KB  -> 2 blocks/CU.
// Cross-block wave overlap (m114/m97 mechanism) covers the per-step drain:
// while this block sits in vmcnt(0)+barrier, the co-resident block's waves
// issue MFMA, and vice versa. No intra-block counted-vmcnt games (rounds
// 5/7/8 showed them null-or-racy at 1 block/CU).
// XOR chunk swizzle sc = c ^ ((r>>1)&3) via pre-swizzled global source,
// linear DMA dest (rounds 6-7 verified: SQ_LDS_BANK_CONFLICT = 0).
// Loop (provably race-free): stage t+1 -> nxt; read 12 b128 of t from cur;
// 32 MFMA; lgkm(0) [reads done]; vmcnt(0) [t+1 landed]; barrier.
// Block mapping (round-3 verified): concurrent set covers ALL 32 A-panels;
// inputs (100 MB int8) L3-resident.

__global__ __launch_bounds__(512, 4)
void gemm_i8_kernel(const int8_t* __restrict__ A, const int8_t* __restrict__ Wt,
                    const float* __restrict__ scale, const float* __restrict__ sx,
                    float* __restrict__ C) {
    __shared__ int8_t lds[2 * 32768];

    const int wg = (int)blockIdx.x;
    const int rr = wg >> 8;                   // round 0..7
    const int ii = wg & 255;
    const int bm = ii & 31;                   // all 32 A-panels each round
    const int bn = rr * 8 + (ii >> 5);        // 8 fresh B-panels per round

    const int tid  = threadIdx.x;
    const int lane = tid & 63;
    const int wid  = tid >> 6;
    const int wm   = wid >> 2;        // 0..1 (128 rows)
    const int wn   = wid & 3;         // 0..3 (64 cols)
    const int l15  = lane & 15;
    const int c16  = lane >> 4;       // 0..3 = logical k-chunk (16 i8)

    // fragment byte offset within a 16-KB plane
    const int axor = (l15 >> 1) & 3;
    const int fro  = l15 * 64 + ((c16 ^ axor) << 4);

    // staging: thread covers plane slots s0 = tid, s1 = 512+tid
    const int s0 = tid, s1 = 512 + tid;
    const int soff0 = (s0 >> 2) * KDIM + ((((s0 & 3) ^ ((s0 >> 3) & 3))) << 4);
    const int soff1 = (s1 >> 2) * KDIM + ((((s1 & 3) ^ ((s1 >> 3) & 3))) << 4);
    const int d0 = s0 * 16, d1 = s1 * 16;

    const int8_t* Ab = A  + (long)bm * 256 * KDIM;
    const int8_t* Wb = Wt + (long)bn * 256 * KDIM;

#define STAGE(bb, P, base, tt)                                                      \
    do {                                                                            \
        gload_lds16((base) + soff0 + (tt) * 64, &lds[(bb) + (P) * 16384 + d0]);     \
        gload_lds16((base) + soff1 + (tt) * 64, &lds[(bb) + (P) * 16384 + d1]);     \
    } while (0)

#define RDALL(BB)                                                                   \
    do {                                                                            \
        _Pragma("unroll")                                                           \
        for (int i_ = 0; i_ < 8; ++i_)                                              \
            aF[i_] = *(const i32x4*)&lds[(BB) + (wm * 128 + i_ * 16) * 64 + fro];   \
        _Pragma("unroll")                                                           \
        for (int j_ = 0; j_ < 4; ++j_)                                              \
            bF[j_] = *(const i32x4*)&lds[(BB) + 16384 + (wn * 64 + j_ * 16) * 64 + fro]; \
    } while (0)

#define MFMAALL()                                                                   \
    do {                                                                            \
        __builtin_amdgcn_sched_barrier(0);                                          \
        __builtin_amdgcn_s_setprio(1);                                              \
        _Pragma("unroll")                                                           \
        for (int i_ = 0; i_ < 8; ++i_)                                              \
            _Pragma("unroll")                                                       \
            for (int j_ = 0; j_ < 4; ++j_)                                          \
                acc[i_][j_] = MFMA8(aF[i_], bF[j_], acc[i_][j_]);                   \
        __builtin_amdgcn_s_setprio(0);                                              \
        __builtin_amdgcn_sched_barrier(0);                                          \
    } while (0)

    i32x4 acc[8][4];
#pragma unroll
    for (int i = 0; i < 8; ++i)
#pragma unroll
        for (int j = 0; j < 4; ++j) acc[i][j] = (i32x4){0, 0, 0, 0};

    i32x4 aF[8], bF[4];

    // prologue: stage step 0 into buf 0; drain; barrier
    STAGE(0, 0, Ab, 0);
    STAGE(0, 1, Wb, 0);
    asm volatile("s_waitcnt vmcnt(0)" ::: "memory");
    __builtin_amdgcn_s_barrier();

    for (int t = 0; t < NT; ++t) {
        const int cur = (t & 1) << 15;
        const int nxt = cur ^ 32768;
        const bool pf = (t + 1 < NT);

        // issue next-step DMA first (max in-flight time under reads+MFMA)
        if (pf) { STAGE(nxt, 0, Ab, t + 1); STAGE(nxt, 1, Wb, t + 1); }

        RDALL(cur);          // 12 x ds_read_b128 (compiler emits counted lgkm)
        MFMAALL();           // 32 MFMA, setprio-wrapped

        asm volatile("s_waitcnt lgkmcnt(0)" ::: "memory");   // reads of cur done (WAR)
        if (pf) asm volatile("s_waitcnt vmcnt(0)" ::: "memory"); // t+1 landed
        __builtin_amdgcn_s_barrier();
    }
#undef STAGE
#undef RDALL
#undef MFMAALL

    // epilogue: D mapping col=lane&15, row=(lane>>4)*4+reg (m89-verified)
    const long rowA0 = (long)bm * 256 + wm * 128;
    const int  colB0 = bn * 256 + wn * 64;
    float scj[4];
#pragma unroll
    for (int j = 0; j < 4; ++j) scj[j] = scale[colB0 + j * 16 + l15];
#pragma unroll
    for (int i = 0; i < 8; ++i) {
        const long rbase = rowA0 + i * 16 + c16 * 4;
        const float4 s4 = *(const float4*)(sx + rbase);
#pragma unroll
        for (int j = 0; j < 4; ++j) {
            float* cp = C + rbase * NDIM + colB0 + j * 16 + l15;
            cp[0 * (long)NDIM] = (float)acc[i][j][0] * scj[j] * s4.x;
            cp[1 * (long)NDIM] = (float)acc[i][j][1] * scj[j] * s4.y;
            cp[2 * (long)NDIM] = (float)acc[i][j][2] * scj[j] * s4.z;
            cp[3 * (long)NDIM] = (float)acc[i][j][3] * scj[j] * s4.w;
        }
    }
}

// ---------------- safety fallback (no workspace needed, fp32, slow) ----------------

__global__ __launch_bounds__(256)
void fallback_kernel(const float* __restrict__ x, const int* __restrict__ q,
                     const float* __restrict__ scale, const int* __restrict__ zp,
                     float* __restrict__ out) {
    __shared__ float sA[64][17];
    __shared__ float sB[64][17];
    const int bn = (int)blockIdx.x % (NDIM / 64);
    const int bm = (int)blockIdx.x / (NDIM / 64);
    const int t  = threadIdx.x;
    const int tx = t & 15, ty = t >> 4;
    const long rowA = (long)bm * 64, rowB = (long)bn * 64;
    float acc[4][4] = {};
    for (int k0 = 0; k0 < KDIM; k0 += 16) {
#pragma unroll
        for (int i = 0; i < 4; ++i) {
            const int e = t + i * 256;
            const int r = e >> 4, c = e & 15;
            sA[r][c] = x[(rowA + r) * KDIM + k0 + c];
            const int o = (int)rowB + r;
            sB[r][c] = (float)(q[(long)o * KDIM + k0 + c] - zp[o]) * scale[o];
        }
        __syncthreads();
#pragma unroll
        for (int kk = 0; kk < 16; ++kk) {
            float a[4], b[4];
#pragma unroll
            for (int i = 0; i < 4; ++i) a[i] = sA[ty * 4 + i][kk];
#pragma unroll
            for (int j = 0; j < 4; ++j) b[j] = sB[tx * 4 + j][kk];
#pragma unroll
            for (int i = 0; i < 4; ++i)
#pragma unroll
                for (int j = 0; j < 4; ++j) acc[i][j] += a[i] * b[j];
        }
        __syncthreads();
    }
#pragma unroll
    for (int i = 0; i < 4; ++i) {
        const long r = rowA + ty * 4 + i;
#pragma unroll
        for (int j = 0; j < 4; ++j)
            out[r * NDIM + rowB + tx * 4 + j] = acc[i][j];
    }
}

// ---------------- launch ----------------

extern "C" void kernel_launch(void* const* d_in, const int* in_sizes, int n_in,
                              void* d_out, int out_size, void* d_ws, size_t ws_size,
                              hipStream_t stream) {
    const float* x     = (const float*)d_in[0];
    const int*   qw    = (const int*)d_in[1];
    const float* scale = (const float*)d_in[2];
    const int*   zp    = (const int*)d_in[3];
    float*       out   = (float*)d_out;

    const size_t needA  = (size_t)MDIM * KDIM;          // 33.5 MB int8
    const size_t needW  = (size_t)NDIM * KDIM;          // 67.1 MB int8
    const size_t needSx = (size_t)MDIM * sizeof(float); // 32 KB

    if (ws_size >= needA + needW + needSx) {
        int8_t* xq = (int8_t*)d_ws;
        int8_t* wq = xq + needA;
        float*  sx = (float*)((char*)d_ws + needA + needW);
        quant_x_kernel<<<MDIM, 256, 0, stream>>>(x, xq, sx);
        quant_w_kernel<<<(NDIM * (KDIM / 16)) / 256, 256, 0, stream>>>(qw, zp, wq);
        gemm_i8_kernel<<<(MDIM / 256) * (NDIM / 256), 512, 0, stream>>>(xq, wq, scale, sx, out);
    } else {
        fallback_kernel<<<(MDIM / 64) * (NDIM / 64), 256, 0, stream>>>(x, qw, scale, zp, out);
    }
}

// Round 10
// 678.750 us; speedup vs baseline: 6.8651x; 6.8651x over previous
//
#include <hip/hip_runtime.h>
#include <stdint.h>

#define MDIM 8192
#define NDIM 16384
#define KDIM 4096
#define NT   64          // K-steps of 64

typedef __attribute__((ext_vector_type(4))) int i32x4;

__device__ __forceinline__ void gload_lds16(const void* g, void* l) {
    __builtin_amdgcn_global_load_lds(
        (const __attribute__((address_space(1))) void*)g,
        (__attribute__((address_space(3))) void*)l,
        16, 0, 0);
}

__device__ __forceinline__ i32x4 MFMA8(i32x4 a, i32x4 b, i32x4 c) {
    return __builtin_amdgcn_mfma_i32_16x16x64_i8(a, b, c, 0, 0, 0);
}

// ---------------- quantization kernels (unchanged, round-6 verified) ----------------

__global__ __launch_bounds__(256)
void quant_x_kernel(const float* __restrict__ x, int8_t* __restrict__ xq,
                    float* __restrict__ sx) {
    const int row = (int)blockIdx.x;
    const float* xr = x + (long)row * KDIM;
    const int t = threadIdx.x;
    float v[16];
#pragma unroll
    for (int i = 0; i < 4; ++i)
        *(float4*)&v[i * 4] = ((const float4*)xr)[t + 256 * i];
    float m = 0.f;
#pragma unroll
    for (int i = 0; i < 16; ++i) m = fmaxf(m, fabsf(v[i]));
#pragma unroll
    for (int off = 32; off >= 1; off >>= 1) m = fmaxf(m, __shfl_xor(m, off));
    __shared__ float red[4];
    if ((t & 63) == 0) red[t >> 6] = m;
    __syncthreads();
    m = fmaxf(fmaxf(red[0], red[1]), fmaxf(red[2], red[3]));
    m = fmaxf(m, 1e-20f);
    const float inv = 127.0f / m;
    if (t == 0) sx[row] = m * (1.0f / 127.0f);
    int* qo = (int*)(xq + (long)row * KDIM);
#pragma unroll
    for (int i = 0; i < 4; ++i) {
        union { int8_t c[4]; int w; } o;
#pragma unroll
        for (int j = 0; j < 4; ++j)
            o.c[j] = (int8_t)__float2int_rn(v[i * 4 + j] * inv);
        qo[t + 256 * i] = o.w;
    }
}

__global__ __launch_bounds__(256)
void quant_w_kernel(const int* __restrict__ q, const int* __restrict__ zp,
                    int8_t* __restrict__ wq) {
    const long i = (long)blockIdx.x * 256 + threadIdx.x;
    const long e = i * 16;
    const int o = (int)(e >> 12);          // KDIM = 4096
    const int z = zp[o];
    union { int8_t c[16]; int4 v; } r;
#pragma unroll
    for (int b = 0; b < 4; ++b) {
        int4 a = ((const int4*)(q + e))[b];
        r.c[b * 4 + 0] = (int8_t)(a.x - z);
        r.c[b * 4 + 1] = (int8_t)(a.y - z);
        r.c[b * 4 + 2] = (int8_t)(a.z - z);
        r.c[b * 4 + 3] = (int8_t)(a.w - z);
    }
    *(int4*)(wq + e) = r.v;
}

// --- 256x256 8-wave int8 GEMM: 3-buf, 4-phase/K-tile, ONE counted vmcnt(4)/tile ---
// C[m,n] = scale[n] * sx[m] * sum_k xq[m,k] * wq[n,k]   (i32 accum, exact)
// LDS: 3 bufs x 32 KB. Buf layout: Ah0[0,8K) Ah1[8K,16K) Bh0[16K,24K) Bh1[24K,32K);
// each half-plane (128r x 64B) = ONE gload_lds line (512 thr x 16 B).
// XOR chunk swizzle sc = c ^ ((r>>1)&3) via pre-swizzled global source, linear
// DMA dest (rounds 6-7 verified: SQ_LDS_BANK_CONFLICT = 0, absmax 28).
//
// Per tile t (buf cb=t%3), 4 phases:
//   ph0: read aLo(4)+bLo(2); stage Ah0(t+2)->fb;          bar; lgkm0; 8 MFMA q(0,0)
//   ph1: read aHi(4);        stage Bh0(t+2)->fb;          bar; lgkm0; 8 MFMA q(4,0)
//   ph2: read bHi(2);        stage Ah1(t+2)->fb;          bar; lgkm0; 8 MFMA q(0,2)
//   ph3:                     stage Bh1(t+2)->fb; vmcnt(4);bar;        8 MFMA q(4,2)
// No barrier between a phase's MFMA and the next phase's reads -> wave skew
// overlaps reads with other waves' MFMA (2 waves/SIMD).
// RAW LEDGER (1 load/phase/wave, fixed order): vmcnt(4) at ph3(t-1) leaves only
// tile t+1's 4 stages outstanding => tile t FULLY landed (incl. Bh1, read as
// bLo by wn>=2) before ph0(t). Prologue: 8 loads (tiles 0,1), vmcnt(4) => tile
// 0 landed. WAR: region staged at ph_k(t) was last read ph_k(t-1), drained by
// that lgkm(0); >=1 barrier before the DMA issues. Tail: clamped dummy stages
// keep the ledger uniform; fb is never a live read buffer (3-buf rotation).
//
// Block mapping (round-3 verified): round = 256 concurrent blocks covers ALL
// 32 A-panels x 8 B-panels; inputs (100 MB int8) L3-resident.

__global__ __launch_bounds__(512, 2)
void gemm_i8_kernel(const int8_t* __restrict__ A, const int8_t* __restrict__ Wt,
                    const float* __restrict__ scale, const float* __restrict__ sx,
                    float* __restrict__ C) {
    __shared__ int8_t lds[3 * 32768];

    const int wg = (int)blockIdx.x;
    const int rr = wg >> 8;                   // round 0..7
    const int ii = wg & 255;
    const int bm = ii & 31;                   // all 32 A-panels each round
    const int bn = rr * 8 + (ii >> 5);        // 8 fresh B-panels per round

    const int tid  = threadIdx.x;
    const int lane = tid & 63;
    const int wid  = tid >> 6;
    const int wm   = wid >> 2;        // 0..1 (128 rows)
    const int wn   = wid & 3;         // 0..3 (64 cols)
    const int l15  = lane & 15;
    const int c16  = lane >> 4;       // 0..3 = logical k-chunk (16 i8)

    // fragment byte offset within a 16-KB plane (A at +0, B at +16384)
    const int axor = (l15 >> 1) & 3;
    const int fro  = l15 * 64 + ((c16 ^ axor) << 4);

    // staging: one line covers 128 rows x 64 B; thread tid -> row tid>>2,
    // phys chunk tid&3, global logical chunk (tid&3)^((tid>>3)&3)
    const int soff = (tid >> 2) * KDIM + ((((tid & 3) ^ ((tid >> 3) & 3))) << 4);
    const int dl   = tid * 16;

    const int8_t* Ab  = A  + (long)bm * 256 * KDIM;
    const int8_t* Wb  = Wt + (long)bn * 256 * KDIM;
    const int8_t* Ab2 = Ab + (long)128 * KDIM;
    const int8_t* Wb2 = Wb + (long)128 * KDIM;

#define STG(DSTB, SRC, TT) gload_lds16((SRC) + soff + (TT) * 64, &lds[(DSTB) + dl])

#define RDA(DST, BB, IB)                                                            \
    _Pragma("unroll")                                                               \
    for (int i_ = 0; i_ < 4; ++i_)                                                  \
        DST[i_] = *(const i32x4*)&lds[(BB) + (wm * 128 + ((IB) + i_) * 16) * 64 + fro];

#define RDB2(DST, BB, JB)                                                           \
    _Pragma("unroll")                                                               \
    for (int j_ = 0; j_ < 2; ++j_)                                                  \
        DST[j_] = *(const i32x4*)&lds[(BB) + 16384 + (wn * 64 + ((JB) + j_) * 16) * 64 + fro];

#define MFQ(IB, JB, AS, BS)                                                         \
    do {                                                                            \
        __builtin_amdgcn_sched_barrier(0);                                          \
        __builtin_amdgcn_s_setprio(1);                                              \
        _Pragma("unroll")                                                           \
        for (int i_ = 0; i_ < 4; ++i_)                                              \
            _Pragma("unroll")                                                       \
            for (int j_ = 0; j_ < 2; ++j_)                                          \
                acc[(IB) + i_][(JB) + j_] =                                         \
                    MFMA8(AS[i_], BS[j_], acc[(IB) + i_][(JB) + j_]);               \
        __builtin_amdgcn_s_setprio(0);                                              \
        __builtin_amdgcn_sched_barrier(0);                                          \
    } while (0)

    i32x4 acc[8][4];
#pragma unroll
    for (int i = 0; i < 8; ++i)
#pragma unroll
        for (int j = 0; j < 4; ++j) acc[i][j] = (i32x4){0, 0, 0, 0};

    i32x4 aLo[4], aHi[4], bLo[2], bHi[2];

    int cb = 0, nb = 32768, fb = 65536;

    // prologue: tiles 0,1 in canonical half order (Ah0,Bh0,Ah1,Bh1); tile 0 landed
    STG(cb + 0, Ab, 0); STG(cb + 16384, Wb, 0); STG(cb + 8192, Ab2, 0); STG(cb + 24576, Wb2, 0);
    STG(nb + 0, Ab, 1); STG(nb + 16384, Wb, 1); STG(nb + 8192, Ab2, 1); STG(nb + 24576, Wb2, 1);
    asm volatile("s_waitcnt vmcnt(4)" ::: "memory");
    __builtin_amdgcn_s_barrier();

    for (int t = 0; t < NT; ++t) {
        const int tt = (t + 2 < NT) ? (t + 2) : (NT - 1);   // clamped dummy at tail

        // ---- ph0: read aLo,bLo(t); stage Ah0(t+2) ----
        RDA(aLo, cb, 0);
        RDB2(bLo, cb, 0);
        STG(fb + 0, Ab, tt);
        __builtin_amdgcn_s_barrier();
        asm volatile("s_waitcnt lgkmcnt(0)" ::: "memory");
        MFQ(0, 0, aLo, bLo);

        // ---- ph1: read aHi(t); stage Bh0(t+2) ----
        RDA(aHi, cb, 4);
        STG(fb + 16384, Wb, tt);
        __builtin_amdgcn_s_barrier();
        asm volatile("s_waitcnt lgkmcnt(0)" ::: "memory");
        MFQ(4, 0, aHi, bLo);

        // ---- ph2: read bHi(t); stage Ah1(t+2) ----
        RDB2(bHi, cb, 2);
        STG(fb + 8192, Ab2, tt);
        __builtin_amdgcn_s_barrier();
        asm volatile("s_waitcnt lgkmcnt(0)" ::: "memory");
        MFQ(0, 2, aLo, bHi);

        // ---- ph3: stage Bh1(t+2); counted vmcnt -> tile t+1 landed ----
        STG(fb + 24576, Wb2, tt);
        asm volatile("s_waitcnt vmcnt(4)" ::: "memory");
        __builtin_amdgcn_s_barrier();
        MFQ(4, 2, aHi, bHi);

        const int tb = cb; cb = nb; nb = fb; fb = tb;
    }
#undef STG
#undef RDA
#undef RDB2
#undef MFQ

    // epilogue: D mapping col=lane&15, row=(lane>>4)*4+reg (m89-verified)
    const long rowA0 = (long)bm * 256 + wm * 128;
    const int  colB0 = bn * 256 + wn * 64;
    float scj[4];
#pragma unroll
    for (int j = 0; j < 4; ++j) scj[j] = scale[colB0 + j * 16 + l15];
#pragma unroll
    for (int i = 0; i < 8; ++i) {
        const long rbase = rowA0 + i * 16 + c16 * 4;
        const float4 s4 = *(const float4*)(sx + rbase);
#pragma unroll
        for (int j = 0; j < 4; ++j) {
            float* cp = C + rbase * NDIM + colB0 + j * 16 + l15;
            cp[0 * (long)NDIM] = (float)acc[i][j][0] * scj[j] * s4.x;
            cp[1 * (long)NDIM] = (float)acc[i][j][1] * scj[j] * s4.y;
            cp[2 * (long)NDIM] = (float)acc[i][j][2] * scj[j] * s4.z;
            cp[3 * (long)NDIM] = (float)acc[i][j][3] * scj[j] * s4.w;
        }
    }
}

// ---------------- safety fallback (no workspace needed, fp32, slow) ----------------

__global__ __launch_bounds__(256)
void fallback_kernel(const float* __restrict__ x, const int* __restrict__ q,
                     const float* __restrict__ scale, const int* __restrict__ zp,
                     float* __restrict__ out) {
    __shared__ float sA[64][17];
    __shared__ float sB[64][17];
    const int bn = (int)blockIdx.x % (NDIM / 64);
    const int bm = (int)blockIdx.x / (NDIM / 64);
    const int t  = threadIdx.x;
    const int tx = t & 15, ty = t >> 4;
    const long rowA = (long)bm * 64, rowB = (long)bn * 64;
    float acc[4][4] = {};
    for (int k0 = 0; k0 < KDIM; k0 += 16) {
#pragma unroll
        for (int i = 0; i < 4; ++i) {
            const int e = t + i * 256;
            const int r = e >> 4, c = e & 15;
            sA[r][c] = x[(rowA + r) * KDIM + k0 + c];
            const int o = (int)rowB + r;
            sB[r][c] = (float)(q[(long)o * KDIM + k0 + c] - zp[o]) * scale[o];
        }
        __syncthreads();
#pragma unroll
        for (int kk = 0; kk < 16; ++kk) {
            float a[4], b[4];
#pragma unroll
            for (int i = 0; i < 4; ++i) a[i] = sA[ty * 4 + i][kk];
#pragma unroll
            for (int j = 0; j < 4; ++j) b[j] = sB[tx * 4 + j][kk];
#pragma unroll
            for (int i = 0; i < 4; ++i)
#pragma unroll
                for (int j = 0; j < 4; ++j) acc[i][j] += a[i] * b[j];
        }
        __syncthreads();
    }
#pragma unroll
    for (int i = 0; i < 4; ++i) {
        const long r = rowA + ty * 4 + i;
#pragma unroll
        for (int j = 0; j < 4; ++j)
            out[r * NDIM + rowB + tx * 4 + j] = acc[i][j];
    }
}

// ---------------- launch ----------------

extern "C" void kernel_launch(void* const* d_in, const int* in_sizes, int n_in,
                              void* d_out, int out_size, void* d_ws, size_t ws_size,
                              hipStream_t stream) {
    const float* x     = (const float*)d_in[0];
    const int*   qw    = (const int*)d_in[1];
    const float* scale = (const float*)d_in[2];
    const int*   zp    = (const int*)d_in[3];
    float*       out   = (float*)d_out;

    const size_t needA  = (size_t)MDIM * KDIM;          // 33.5 MB int8
    const size_t needW  = (size_t)NDIM * KDIM;          // 67.1 MB int8
    const size_t needSx = (size_t)MDIM * sizeof(float); // 32 KB

    if (ws_size >= needA + needW + needSx) {
        int8_t* xq = (int8_t*)d_ws;
        int8_t* wq = xq + needA;
        float*  sx = (float*)((char*)d_ws + needA + needW);
        quant_x_kernel<<<MDIM, 256, 0, stream>>>(x, xq, sx);
        quant_w_kernel<<<(NDIM * (KDIM / 16)) / 256, 256, 0, stream>>>(qw, zp, wq);
        gemm_i8_kernel<<<(MDIM / 256) * (NDIM / 256), 512, 0, stream>>>(xq, wq, scale, sx, out);
    } else {
        fallback_kernel<<<(MDIM / 64) * (NDIM / 64), 256, 0, stream>>>(x, qw, scale, zp, out);
    }
}